// Round 5
// baseline (1281.969 us; speedup 1.0000x reference)
//
#include <hip/hip_runtime.h>
#include <hip/hip_bf16.h>
#include <math.h>

#define HW 4096
#define NN 32

typedef __attribute__((ext_vector_type(8))) short bf16x8;
typedef __attribute__((ext_vector_type(4))) float f32x4;

__device__ inline unsigned short bfbits(float a) {
    __hip_bfloat16 h = __float2bfloat16(a);
    unsigned short u;
    __builtin_memcpy(&u, &h, 2);
    return u;
}
__device__ inline unsigned packbf(float a, float b) {
    return (unsigned)bfbits(a) | ((unsigned)bfbits(b) << 16);
}
__device__ inline float bflo(unsigned u) { return __uint_as_float(u << 16); }
__device__ inline float bfhi(unsigned u) { return __uint_as_float(u & 0xffff0000u); }

// ---------------------------------------------------------------------------
// Kernel T: x[n][c][pos] (fp32) -> xT[n][g][pos][c16] (bf16, 32B per pos).
// ---------------------------------------------------------------------------
__global__ __launch_bounds__(256) void transpose_x(const float* __restrict__ x,
                                                   unsigned short* __restrict__ xT)
{
    __shared__ float tile[256 * 17];
    int bx = blockIdx.x;
    int n = bx >> 6, g = (bx >> 4) & 3, chunk = bx & 15;
    int t = threadIdx.x;
    const float* xb = x + (size_t)(n * 64 + g * 16) * HW + chunk * 256;

    #pragma unroll
    for (int r = 0; r < 16; r++) {
        int idx = r * 256 + t;
        int c = idx >> 8, p = idx & 255;
        tile[p * 17 + c] = xb[c * HW + p];
    }
    __syncthreads();

    uint4* ob = (uint4*)(xT + ((size_t)(n * 4 + g) * HW + chunk * 256) * 16);
    #pragma unroll
    for (int r = 0; r < 2; r++) {
        int idx = r * 256 + t;
        int p = idx >> 1, half = idx & 1;
        const float* tp = &tile[p * 17 + half * 8];
        uint4 v;
        v.x = packbf(tp[0], tp[1]);
        v.y = packbf(tp[2], tp[3]);
        v.z = packbf(tp[4], tp[5]);
        v.w = packbf(tp[6], tp[7]);
        ob[idx] = v;
    }
}

// ---------------------------------------------------------------------------
// Bilinear helpers (verified round 3).
// ---------------------------------------------------------------------------
__device__ inline void bilin_setup(int h, int w, int ki, int kj, float dy, float dx,
                                   float* ww, int* ss) {
    float py = (float)(h - 1 + ki) + dy;
    float px = (float)(w - 1 + kj) + dx;
    float y0f = floorf(py), x0f = floorf(px);
    float ly = py - y0f, lx = px - x0f;
    int y0 = (int)y0f, x0 = (int)x0f;
    int y1 = y0 + 1, x1 = x0 + 1;
    float vy0 = (y0 >= 0 && y0 < 64) ? 1.f : 0.f;
    float vy1 = (y1 >= 0 && y1 < 64) ? 1.f : 0.f;
    float vx0 = (x0 >= 0 && x0 < 64) ? 1.f : 0.f;
    float vx1 = (x1 >= 0 && x1 < 64) ? 1.f : 0.f;
    ww[0] = (1.f - ly) * (1.f - lx) * vy0 * vx0;
    ww[1] = (1.f - ly) * lx         * vy0 * vx1;
    ww[2] = ly         * (1.f - lx) * vy1 * vx0;
    ww[3] = ly         * lx         * vy1 * vx1;
    int yc0 = min(max(y0, 0), 63) * 64, yc1 = min(max(y1, 0), 63) * 64;
    int xc0 = min(max(x0, 0), 63),      xc1 = min(max(x1, 0), 63);
    ss[0] = yc0 + xc0; ss[1] = yc0 + xc1; ss[2] = yc1 + xc0; ss[3] = yc1 + xc1;
}

__device__ inline void bilin8(uint4 A, uint4 B, uint4 C, uint4 D,
                              const float* ww, float* val) {
    const unsigned* ua = (const unsigned*)&A;
    const unsigned* ub = (const unsigned*)&B;
    const unsigned* uc = (const unsigned*)&C;
    const unsigned* ud = (const unsigned*)&D;
    #pragma unroll
    for (int j = 0; j < 4; j++) {
        val[2*j]   = ww[0]*bflo(ua[j]) + ww[1]*bflo(ub[j]) + ww[2]*bflo(uc[j]) + ww[3]*bflo(ud[j]);
        val[2*j+1] = ww[0]*bfhi(ua[j]) + ww[1]*bfhi(ub[j]) + ww[2]*bfhi(uc[j]) + ww[3]*bfhi(ud[j]);
    }
}

// ---------------------------------------------------------------------------
// Kernel A3: offset conv as im2col-LDS + MFMA 16x16x32 bf16.
// grid 2048 = 32n*4g*16chunk ; block 256 = 4 waves ; 256 positions/block.
// K = 144 processed as 5 pairs of taps (K=32 each, tap 9 zero in A operand).
// V tile layout: V[pos 0..255][k 0..31] bf16, row stride 80B (5 uint4, 1 pad).
// M = 18 -> two 16-row M-tiles (second has 2 live rows).
// ---------------------------------------------------------------------------
__global__ __launch_bounds__(256) void off_conv3(const unsigned short* __restrict__ xT,
                                                 const float* __restrict__ w_off,
                                                 const float* __restrict__ b_off,
                                                 __hip_bfloat16* __restrict__ off)
{
    __shared__ uint4 vt[1280];   // 256 rows * 5 uint4
    int bx = blockIdx.x;
    int n = bx >> 6, g = (bx >> 4) & 3, chunk = bx & 15;
    int t = threadIdx.x;
    int lane = t & 63, wv = t >> 6;
    int nn = lane & 15, q = lane >> 4;

    // A fragments: A[m=lane&15][k=q*8+j], k_local = t2*16 + c, tap = kp*2+t2
    bf16x8 a0[5], a1[5];
    #pragma unroll 1
    for (int kp = 0; kp < 5; kp++) {
        #pragma unroll
        for (int j = 0; j < 8; j++) {
            int k = q * 8 + j;
            int t2 = k >> 4, c = k & 15;
            int tap = kp * 2 + t2;
            float w0 = (tap < 9) ? w_off[(g * 18 + nn) * 144 + c * 9 + tap] : 0.f;
            float w1 = (tap < 9 && nn < 2) ? w_off[(g * 18 + 16 + nn) * 144 + c * 9 + tap] : 0.f;
            a0[kp][j] = (short)bfbits(w0);
            a1[kp][j] = (short)bfbits(w1);
        }
    }

    // accumulators init with bias: D row = q*4+r
    f32x4 acc0[4], acc1[4];
    #pragma unroll
    for (int r = 0; r < 4; r++) {
        float bv0 = b_off[g * 18 + q * 4 + r];
        int d1 = 16 + q * 4 + r;
        float bv1 = (d1 < 18) ? b_off[g * 18 + d1] : 0.f;
        #pragma unroll
        for (int s = 0; s < 4; s++) { acc0[s][r] = bv0; acc1[s][r] = bv1; }
    }

    int pos = chunk * 256 + t;
    int h = pos >> 6, w = pos & 63;
    const uint4* xb = (const uint4*)xT + (size_t)(n * 4 + g) * HW * 2;

    #pragma unroll 1
    for (int kp = 0; kp < 5; kp++) {
        // produce: V[t][t2*16+c] = xT[shifted pos] (already bf16 -> copy)
        #pragma unroll
        for (int t2 = 0; t2 < 2; t2++) {
            int tap = kp * 2 + t2;
            if (tap < 9) {
                int ki = tap / 3, kj = tap - ki * 3;
                int r0 = h - 1 + ki, c0 = w - 1 + kj;
                bool valid = (r0 >= 0) && (r0 < 64) && (c0 >= 0) && (c0 < 64);
                int idx = valid ? (r0 * 64 + c0) : 0;
                uint4 v0 = xb[idx * 2], v1 = xb[idx * 2 + 1];
                if (!valid) { v0.x = v0.y = v0.z = v0.w = 0u; v1 = v0; }
                vt[t * 5 + t2 * 2]     = v0;
                vt[t * 5 + t2 * 2 + 1] = v1;
            }
        }
        __syncthreads();
        // consume: 4 subtiles x 2 M-tiles
        #pragma unroll
        for (int s = 0; s < 4; s++) {
            int lp = (wv * 4 + s) * 16 + nn;
            uint4 braw = vt[lp * 5 + q];
            bf16x8 bfrag = *(bf16x8*)&braw;
            acc0[s] = __builtin_amdgcn_mfma_f32_16x16x32_bf16(a0[kp], bfrag, acc0[s], 0, 0, 0);
            acc1[s] = __builtin_amdgcn_mfma_f32_16x16x32_bf16(a1[kp], bfrag, acc1[s], 0, 0, 0);
        }
        __syncthreads();
    }

    // epilogue: store bf16 offsets. D: col(pos)=lane&15, row(d)=q*4+r.
    __hip_bfloat16* ob = off + (size_t)(n * 72 + g * 18) * HW;
    #pragma unroll
    for (int s = 0; s < 4; s++) {
        int p = chunk * 256 + (wv * 4 + s) * 16 + nn;
        #pragma unroll
        for (int r = 0; r < 4; r++)
            ob[(q * 4 + r) * HW + p] = __float2bfloat16(acc0[s][r]);
        if (q == 0) {
            ob[16 * HW + p] = __float2bfloat16(acc1[s][0]);
            ob[17 * HW + p] = __float2bfloat16(acc1[s][1]);
        }
    }
}

// ---------------------------------------------------------------------------
// Kernel B3: deformable conv as bilinear-im2col-LDS + MFMA 16x16x32 bf16.
// grid 2048 = 32n*4g*16chunk ; block 256 = 4 waves ; 256 positions/block.
// ---------------------------------------------------------------------------
__global__ __launch_bounds__(256) void deform_conv3(const unsigned short* __restrict__ xT,
                                                    const __hip_bfloat16* __restrict__ off,
                                                    const float* __restrict__ w_dc,
                                                    const float* __restrict__ b_dc,
                                                    float* __restrict__ outpre)
{
    __shared__ uint4 vt[1280];
    int bx = blockIdx.x;
    int n = bx >> 6, g = (bx >> 4) & 3, chunk = bx & 15;
    int t = threadIdx.x;
    int lane = t & 63, wv = t >> 6;
    int nn = lane & 15, q = lane >> 4;

    bf16x8 afrag[5];
    #pragma unroll 1
    for (int kp = 0; kp < 5; kp++) {
        #pragma unroll
        for (int j = 0; j < 8; j++) {
            int k = q * 8 + j;
            int t2 = k >> 4, c = k & 15;
            int tap = kp * 2 + t2;
            float wvv = (tap < 9) ? w_dc[(g * 16 + nn) * 144 + c * 9 + tap] : 0.f;
            afrag[kp][j] = (short)bfbits(wvv);
        }
    }

    f32x4 acc[4];
    #pragma unroll
    for (int r = 0; r < 4; r++) {
        float bv = b_dc[g * 16 + q * 4 + r];
        #pragma unroll
        for (int s = 0; s < 4; s++) acc[s][r] = bv;
    }

    int pos = chunk * 256 + t;
    int h = pos >> 6, w = pos & 63;
    const uint4* xb = (const uint4*)xT + (size_t)(n * 4 + g) * HW * 2;
    const __hip_bfloat16* ob = off + (size_t)(n * 72 + g * 18) * HW;

    #pragma unroll 1
    for (int kp = 0; kp < 5; kp++) {
        #pragma unroll
        for (int t2 = 0; t2 < 2; t2++) {
            int tap = kp * 2 + t2;
            if (tap < 9) {
                int ki = tap / 3, kj = tap - ki * 3;
                float dy = __bfloat162float(ob[(2 * tap + 0) * HW + pos]);
                float dx = __bfloat162float(ob[(2 * tap + 1) * HW + pos]);
                float ww[4]; int ss[4];
                bilin_setup(h, w, ki, kj, dy, dx, ww, ss);
                float v0[8], v1[8];
                bilin8(xb[ss[0] * 2], xb[ss[1] * 2], xb[ss[2] * 2], xb[ss[3] * 2], ww, v0);
                bilin8(xb[ss[0] * 2 + 1], xb[ss[1] * 2 + 1],
                       xb[ss[2] * 2 + 1], xb[ss[3] * 2 + 1], ww, v1);
                uint4 lo, hi;
                lo.x = packbf(v0[0], v0[1]); lo.y = packbf(v0[2], v0[3]);
                lo.z = packbf(v0[4], v0[5]); lo.w = packbf(v0[6], v0[7]);
                hi.x = packbf(v1[0], v1[1]); hi.y = packbf(v1[2], v1[3]);
                hi.z = packbf(v1[4], v1[5]); hi.w = packbf(v1[6], v1[7]);
                vt[t * 5 + t2 * 2]     = lo;
                vt[t * 5 + t2 * 2 + 1] = hi;
            }
        }
        __syncthreads();
        #pragma unroll
        for (int s = 0; s < 4; s++) {
            int lp = (wv * 4 + s) * 16 + nn;
            uint4 braw = vt[lp * 5 + q];
            bf16x8 bfrag = *(bf16x8*)&braw;
            acc[s] = __builtin_amdgcn_mfma_f32_16x16x32_bf16(afrag[kp], bfrag, acc[s], 0, 0, 0);
        }
        __syncthreads();
    }

    float* op = outpre + (size_t)(n * 64 + g * 16) * HW;
    #pragma unroll
    for (int s = 0; s < 4; s++) {
        int p = chunk * 256 + (wv * 4 + s) * 16 + nn;
        #pragma unroll
        for (int r = 0; r < 4; r++)
            op[(q * 4 + r) * HW + p] = acc[s][r];
    }
}

// ---------------------------------------------------------------------------
// Kernel C: per-(n,cout) spatial mean/var + exact GELU + transposed store.
// ---------------------------------------------------------------------------
__global__ __launch_bounds__(256) void norm_gelu(const float* __restrict__ outpre,
                                                 float* __restrict__ out)
{
    __shared__ float red[8];
    int bx = blockIdx.x;
    int n  = bx >> 6;
    int co = bx & 63;
    int t  = threadIdx.x;

    const float4* base = (const float4*)(outpre + (size_t)(n * 64 + co) * HW);
    float4 v[4];
    float s = 0.f;
    #pragma unroll
    for (int r = 0; r < 4; r++) {
        v[r] = base[t + r * 256];
        s += v[r].x + v[r].y + v[r].z + v[r].w;
    }
    #pragma unroll
    for (int o2 = 32; o2 > 0; o2 >>= 1) s += __shfl_down(s, o2, 64);
    int wid = t >> 6, lane = t & 63;
    if (lane == 0) red[wid] = s;
    __syncthreads();
    float mean = (red[0] + red[1] + red[2] + red[3]) * (1.f / 4096.f);

    float sq = 0.f;
    #pragma unroll
    for (int r = 0; r < 4; r++) {
        float a = v[r].x - mean, b = v[r].y - mean;
        float c = v[r].z - mean, d = v[r].w - mean;
        sq += a * a + b * b + c * c + d * d;
    }
    #pragma unroll
    for (int o2 = 32; o2 > 0; o2 >>= 1) sq += __shfl_down(sq, o2, 64);
    if (lane == 0) red[4 + wid] = sq;
    __syncthreads();
    float var  = (red[4] + red[5] + red[6] + red[7]) * (1.f / 4096.f);
    float rstd = rsqrtf(var + 1e-5f);

    int b = n >> 3, d = n & 7;
    float4* outp = (float4*)(out + ((size_t)(b * 64 + co) * 8 + d) * HW);
    #pragma unroll
    for (int r = 0; r < 4; r++) {
        float xs[4] = {v[r].x, v[r].y, v[r].z, v[r].w};
        float4 res;
        float* rp = (float*)&res;
        #pragma unroll
        for (int qq = 0; qq < 4; qq++) {
            float xn = (xs[qq] - mean) * rstd;
            rp[qq] = 0.5f * xn * (1.f + erff(xn * 0.70710678118654752f));
        }
        outp[t + r * 256] = res;
    }
}

// ---------------------------------------------------------------------------
extern "C" void kernel_launch(void* const* d_in, const int* in_sizes, int n_in,
                              void* d_out, int out_size, void* d_ws, size_t ws_size,
                              hipStream_t stream) {
    const float* x     = (const float*)d_in[0];
    const float* w_off = (const float*)d_in[1];
    const float* b_off = (const float*)d_in[2];
    const float* w_dc  = (const float*)d_in[3];
    const float* b_dc  = (const float*)d_in[4];
    float* out = (float*)d_out;

    __hip_bfloat16* xTb  = (__hip_bfloat16*)d_ws;              // 16.78 MB
    __hip_bfloat16* offb = xTb + (size_t)NN * 4 * HW * 16;     // 18.87 MB
    float* outpre = (float*)(offb + (size_t)NN * 72 * HW);     // 33.55 MB

    transpose_x <<<2048, 256, 0, stream>>>(x, (unsigned short*)xTb);
    off_conv3   <<<2048, 256, 0, stream>>>((const unsigned short*)xTb, w_off, b_off, offb);
    deform_conv3<<<2048, 256, 0, stream>>>((const unsigned short*)xTb, offb, w_dc, b_dc, outpre);
    norm_gelu   <<<2048, 256, 0, stream>>>(outpre, out);
}

// Round 6
// 233.110 us; speedup vs baseline: 5.4994x; 5.4994x over previous
//
#include <hip/hip_runtime.h>
#include <hip/hip_bf16.h>
#include <math.h>

#define HW 4096
#define NN 32

typedef __attribute__((ext_vector_type(8))) short bf16x8;
typedef __attribute__((ext_vector_type(4))) float f32x4;

__device__ inline unsigned short bfbits(float a) {
    __hip_bfloat16 h = __float2bfloat16(a);
    unsigned short u;
    __builtin_memcpy(&u, &h, 2);
    return u;
}
__device__ inline unsigned packbf(float a, float b) {
    return (unsigned)bfbits(a) | ((unsigned)bfbits(b) << 16);
}
__device__ inline float bflo(unsigned u) { return __uint_as_float(u << 16); }
__device__ inline float bfhi(unsigned u) { return __uint_as_float(u & 0xffff0000u); }

// ---------------------------------------------------------------------------
// Kernel T: x[n][c][pos] (fp32) -> xT[n][g][pos][c16] (bf16, 32B per pos).
// ---------------------------------------------------------------------------
__global__ __launch_bounds__(256) void transpose_x(const float* __restrict__ x,
                                                   unsigned short* __restrict__ xT)
{
    __shared__ float tile[256 * 17];
    int bx = blockIdx.x;
    int n = bx >> 6, g = (bx >> 4) & 3, chunk = bx & 15;
    int t = threadIdx.x;
    const float* xb = x + (size_t)(n * 64 + g * 16) * HW + chunk * 256;

    #pragma unroll
    for (int r = 0; r < 16; r++) {
        int idx = r * 256 + t;
        int c = idx >> 8, p = idx & 255;
        tile[p * 17 + c] = xb[c * HW + p];
    }
    __syncthreads();

    uint4* ob = (uint4*)(xT + ((size_t)(n * 4 + g) * HW + chunk * 256) * 16);
    #pragma unroll
    for (int r = 0; r < 2; r++) {
        int idx = r * 256 + t;
        int p = idx >> 1, half = idx & 1;
        const float* tp = &tile[p * 17 + half * 8];
        uint4 v;
        v.x = packbf(tp[0], tp[1]);
        v.y = packbf(tp[2], tp[3]);
        v.z = packbf(tp[4], tp[5]);
        v.w = packbf(tp[6], tp[7]);
        ob[idx] = v;
    }
}

// ---------------------------------------------------------------------------
// Bilinear helpers (verified round 3).
// ---------------------------------------------------------------------------
__device__ inline void bilin_setup(int h, int w, int ki, int kj, float dy, float dx,
                                   float* ww, int* ss) {
    float py = (float)(h - 1 + ki) + dy;
    float px = (float)(w - 1 + kj) + dx;
    float y0f = floorf(py), x0f = floorf(px);
    float ly = py - y0f, lx = px - x0f;
    int y0 = (int)y0f, x0 = (int)x0f;
    int y1 = y0 + 1, x1 = x0 + 1;
    float vy0 = (y0 >= 0 && y0 < 64) ? 1.f : 0.f;
    float vy1 = (y1 >= 0 && y1 < 64) ? 1.f : 0.f;
    float vx0 = (x0 >= 0 && x0 < 64) ? 1.f : 0.f;
    float vx1 = (x1 >= 0 && x1 < 64) ? 1.f : 0.f;
    ww[0] = (1.f - ly) * (1.f - lx) * vy0 * vx0;
    ww[1] = (1.f - ly) * lx         * vy0 * vx1;
    ww[2] = ly         * (1.f - lx) * vy1 * vx0;
    ww[3] = ly         * lx         * vy1 * vx1;
    int yc0 = min(max(y0, 0), 63) * 64, yc1 = min(max(y1, 0), 63) * 64;
    int xc0 = min(max(x0, 0), 63),      xc1 = min(max(x1, 0), 63);
    ss[0] = yc0 + xc0; ss[1] = yc0 + xc1; ss[2] = yc1 + xc0; ss[3] = yc1 + xc1;
}

__device__ inline void bilin8(uint4 A, uint4 B, uint4 C, uint4 D,
                              const float* ww, float* val) {
    const unsigned* ua = (const unsigned*)&A;
    const unsigned* ub = (const unsigned*)&B;
    const unsigned* uc = (const unsigned*)&C;
    const unsigned* ud = (const unsigned*)&D;
    #pragma unroll
    for (int j = 0; j < 4; j++) {
        val[2*j]   = ww[0]*bflo(ua[j]) + ww[1]*bflo(ub[j]) + ww[2]*bflo(uc[j]) + ww[3]*bflo(ud[j]);
        val[2*j+1] = ww[0]*bfhi(ua[j]) + ww[1]*bfhi(ub[j]) + ww[2]*bfhi(uc[j]) + ww[3]*bfhi(ud[j]);
    }
}

// ---------------------------------------------------------------------------
// Kernel A3: offset conv as im2col-LDS + MFMA 16x16x32 bf16.
// grid 2048 = 32n*4g*16chunk ; block 256 = 4 waves ; 256 positions/block.
// K = 144 as 5 tap-pairs (K=32 each, tap 9 zeroed in A operand).
// V tile: V[pos 0..255][k 0..31] bf16, row stride 80B (5 uint4).
// ALL kp loops fully unrolled: register arrays must be statically indexed.
// ---------------------------------------------------------------------------
__global__ __launch_bounds__(256) void off_conv3(const unsigned short* __restrict__ xT,
                                                 const float* __restrict__ w_off,
                                                 const float* __restrict__ b_off,
                                                 __hip_bfloat16* __restrict__ off)
{
    __shared__ uint4 vt[1280];   // 256 rows * 5 uint4
    int bx = blockIdx.x;
    int n = bx >> 6, g = (bx >> 4) & 3, chunk = bx & 15;
    int t = threadIdx.x;
    int lane = t & 63, wv = t >> 6;
    int nn = lane & 15, q = lane >> 4;

    // A fragments: A[m=lane&15][k=q*8+j], k_local = t2*16 + c, tap = kp*2+t2
    bf16x8 a0[5], a1[5];
    #pragma unroll
    for (int kp = 0; kp < 5; kp++) {
        #pragma unroll
        for (int j = 0; j < 8; j++) {
            int k = q * 8 + j;
            int t2 = k >> 4, c = k & 15;
            int tap = kp * 2 + t2;
            float w0 = (tap < 9) ? w_off[(g * 18 + nn) * 144 + c * 9 + tap] : 0.f;
            float w1 = (tap < 9 && nn < 2) ? w_off[(g * 18 + 16 + nn) * 144 + c * 9 + tap] : 0.f;
            a0[kp][j] = (short)bfbits(w0);
            a1[kp][j] = (short)bfbits(w1);
        }
    }

    // accumulators init with bias: D row = q*4+r
    f32x4 acc0[4], acc1[4];
    #pragma unroll
    for (int r = 0; r < 4; r++) {
        float bv0 = b_off[g * 18 + q * 4 + r];
        int d1 = 16 + q * 4 + r;
        float bv1 = (d1 < 18) ? b_off[g * 18 + d1] : 0.f;
        #pragma unroll
        for (int s = 0; s < 4; s++) { acc0[s][r] = bv0; acc1[s][r] = bv1; }
    }

    int pos = chunk * 256 + t;
    int h = pos >> 6, w = pos & 63;
    const uint4* xb = (const uint4*)xT + (size_t)(n * 4 + g) * HW * 2;

    #pragma unroll
    for (int kp = 0; kp < 5; kp++) {
        #pragma unroll
        for (int t2 = 0; t2 < 2; t2++) {
            int tap = kp * 2 + t2;
            if (tap < 9) {
                int ki = tap / 3, kj = tap - ki * 3;
                int r0 = h - 1 + ki, c0 = w - 1 + kj;
                bool valid = (r0 >= 0) && (r0 < 64) && (c0 >= 0) && (c0 < 64);
                int idx = valid ? (r0 * 64 + c0) : 0;
                uint4 v0 = xb[idx * 2], v1 = xb[idx * 2 + 1];
                if (!valid) { v0.x = v0.y = v0.z = v0.w = 0u; v1 = v0; }
                vt[t * 5 + t2 * 2]     = v0;
                vt[t * 5 + t2 * 2 + 1] = v1;
            }
        }
        __syncthreads();
        #pragma unroll
        for (int s = 0; s < 4; s++) {
            int lp = (wv * 4 + s) * 16 + nn;
            uint4 braw = vt[lp * 5 + q];
            bf16x8 bfrag = *(bf16x8*)&braw;
            acc0[s] = __builtin_amdgcn_mfma_f32_16x16x32_bf16(a0[kp], bfrag, acc0[s], 0, 0, 0);
            acc1[s] = __builtin_amdgcn_mfma_f32_16x16x32_bf16(a1[kp], bfrag, acc1[s], 0, 0, 0);
        }
        __syncthreads();
    }

    // epilogue: D: col(pos)=lane&15, row(d)=q*4+r.
    __hip_bfloat16* ob = off + (size_t)(n * 72 + g * 18) * HW;
    #pragma unroll
    for (int s = 0; s < 4; s++) {
        int p = chunk * 256 + (wv * 4 + s) * 16 + nn;
        #pragma unroll
        for (int r = 0; r < 4; r++)
            ob[(q * 4 + r) * HW + p] = __float2bfloat16(acc0[s][r]);
        if (q == 0) {
            ob[16 * HW + p] = __float2bfloat16(acc1[s][0]);
            ob[17 * HW + p] = __float2bfloat16(acc1[s][1]);
        }
    }
}

// ---------------------------------------------------------------------------
// Kernel B3: deformable conv as bilinear-im2col-LDS + MFMA 16x16x32 bf16.
// Fully-unrolled kp loops (static register-array indexing).
// ---------------------------------------------------------------------------
__global__ __launch_bounds__(256) void deform_conv3(const unsigned short* __restrict__ xT,
                                                    const __hip_bfloat16* __restrict__ off,
                                                    const float* __restrict__ w_dc,
                                                    const float* __restrict__ b_dc,
                                                    float* __restrict__ outpre)
{
    __shared__ uint4 vt[1280];
    int bx = blockIdx.x;
    int n = bx >> 6, g = (bx >> 4) & 3, chunk = bx & 15;
    int t = threadIdx.x;
    int lane = t & 63, wv = t >> 6;
    int nn = lane & 15, q = lane >> 4;

    bf16x8 afrag[5];
    #pragma unroll
    for (int kp = 0; kp < 5; kp++) {
        #pragma unroll
        for (int j = 0; j < 8; j++) {
            int k = q * 8 + j;
            int t2 = k >> 4, c = k & 15;
            int tap = kp * 2 + t2;
            float wvv = (tap < 9) ? w_dc[(g * 16 + nn) * 144 + c * 9 + tap] : 0.f;
            afrag[kp][j] = (short)bfbits(wvv);
        }
    }

    f32x4 acc[4];
    #pragma unroll
    for (int r = 0; r < 4; r++) {
        float bv = b_dc[g * 16 + q * 4 + r];
        #pragma unroll
        for (int s = 0; s < 4; s++) acc[s][r] = bv;
    }

    int pos = chunk * 256 + t;
    int h = pos >> 6, w = pos & 63;
    const uint4* xb = (const uint4*)xT + (size_t)(n * 4 + g) * HW * 2;
    const __hip_bfloat16* ob = off + (size_t)(n * 72 + g * 18) * HW;

    #pragma unroll
    for (int kp = 0; kp < 5; kp++) {
        #pragma unroll
        for (int t2 = 0; t2 < 2; t2++) {
            int tap = kp * 2 + t2;
            if (tap < 9) {
                int ki = tap / 3, kj = tap - ki * 3;
                float dy = __bfloat162float(ob[(2 * tap + 0) * HW + pos]);
                float dx = __bfloat162float(ob[(2 * tap + 1) * HW + pos]);
                float ww[4]; int ss[4];
                bilin_setup(h, w, ki, kj, dy, dx, ww, ss);
                float v0[8], v1[8];
                bilin8(xb[ss[0] * 2], xb[ss[1] * 2], xb[ss[2] * 2], xb[ss[3] * 2], ww, v0);
                bilin8(xb[ss[0] * 2 + 1], xb[ss[1] * 2 + 1],
                       xb[ss[2] * 2 + 1], xb[ss[3] * 2 + 1], ww, v1);
                uint4 lo, hi;
                lo.x = packbf(v0[0], v0[1]); lo.y = packbf(v0[2], v0[3]);
                lo.z = packbf(v0[4], v0[5]); lo.w = packbf(v0[6], v0[7]);
                hi.x = packbf(v1[0], v1[1]); hi.y = packbf(v1[2], v1[3]);
                hi.z = packbf(v1[4], v1[5]); hi.w = packbf(v1[6], v1[7]);
                vt[t * 5 + t2 * 2]     = lo;
                vt[t * 5 + t2 * 2 + 1] = hi;
            }
        }
        __syncthreads();
        #pragma unroll
        for (int s = 0; s < 4; s++) {
            int lp = (wv * 4 + s) * 16 + nn;
            uint4 braw = vt[lp * 5 + q];
            bf16x8 bfrag = *(bf16x8*)&braw;
            acc[s] = __builtin_amdgcn_mfma_f32_16x16x32_bf16(afrag[kp], bfrag, acc[s], 0, 0, 0);
        }
        __syncthreads();
    }

    float* op = outpre + (size_t)(n * 64 + g * 16) * HW;
    #pragma unroll
    for (int s = 0; s < 4; s++) {
        int p = chunk * 256 + (wv * 4 + s) * 16 + nn;
        #pragma unroll
        for (int r = 0; r < 4; r++)
            op[(q * 4 + r) * HW + p] = acc[s][r];
    }
}

// ---------------------------------------------------------------------------
// Kernel C: per-(n,cout) spatial mean/var + exact GELU + transposed store.
// ---------------------------------------------------------------------------
__global__ __launch_bounds__(256) void norm_gelu(const float* __restrict__ outpre,
                                                 float* __restrict__ out)
{
    __shared__ float red[8];
    int bx = blockIdx.x;
    int n  = bx >> 6;
    int co = bx & 63;
    int t  = threadIdx.x;

    const float4* base = (const float4*)(outpre + (size_t)(n * 64 + co) * HW);
    float4 v[4];
    float s = 0.f;
    #pragma unroll
    for (int r = 0; r < 4; r++) {
        v[r] = base[t + r * 256];
        s += v[r].x + v[r].y + v[r].z + v[r].w;
    }
    #pragma unroll
    for (int o2 = 32; o2 > 0; o2 >>= 1) s += __shfl_down(s, o2, 64);
    int wid = t >> 6, lane = t & 63;
    if (lane == 0) red[wid] = s;
    __syncthreads();
    float mean = (red[0] + red[1] + red[2] + red[3]) * (1.f / 4096.f);

    float sq = 0.f;
    #pragma unroll
    for (int r = 0; r < 4; r++) {
        float a = v[r].x - mean, b = v[r].y - mean;
        float c = v[r].z - mean, d = v[r].w - mean;
        sq += a * a + b * b + c * c + d * d;
    }
    #pragma unroll
    for (int o2 = 32; o2 > 0; o2 >>= 1) sq += __shfl_down(sq, o2, 64);
    if (lane == 0) red[4 + wid] = sq;
    __syncthreads();
    float var  = (red[4] + red[5] + red[6] + red[7]) * (1.f / 4096.f);
    float rstd = rsqrtf(var + 1e-5f);

    int b = n >> 3, d = n & 7;
    float4* outp = (float4*)(out + ((size_t)(b * 64 + co) * 8 + d) * HW);
    #pragma unroll
    for (int r = 0; r < 4; r++) {
        float xs[4] = {v[r].x, v[r].y, v[r].z, v[r].w};
        float4 res;
        float* rp = (float*)&res;
        #pragma unroll
        for (int qq = 0; qq < 4; qq++) {
            float xn = (xs[qq] - mean) * rstd;
            rp[qq] = 0.5f * xn * (1.f + erff(xn * 0.70710678118654752f));
        }
        outp[t + r * 256] = res;
    }
}

// ---------------------------------------------------------------------------
extern "C" void kernel_launch(void* const* d_in, const int* in_sizes, int n_in,
                              void* d_out, int out_size, void* d_ws, size_t ws_size,
                              hipStream_t stream) {
    const float* x     = (const float*)d_in[0];
    const float* w_off = (const float*)d_in[1];
    const float* b_off = (const float*)d_in[2];
    const float* w_dc  = (const float*)d_in[3];
    const float* b_dc  = (const float*)d_in[4];
    float* out = (float*)d_out;

    __hip_bfloat16* xTb  = (__hip_bfloat16*)d_ws;              // 16.78 MB
    __hip_bfloat16* offb = xTb + (size_t)NN * 4 * HW * 16;     // 18.87 MB
    float* outpre = (float*)(offb + (size_t)NN * 72 * HW);     // 33.55 MB

    transpose_x <<<2048, 256, 0, stream>>>(x, (unsigned short*)xTb);
    off_conv3   <<<2048, 256, 0, stream>>>((const unsigned short*)xTb, w_off, b_off, offb);
    deform_conv3<<<2048, 256, 0, stream>>>((const unsigned short*)xTb, offb, w_dc, b_dc, outpre);
    norm_gelu   <<<2048, 256, 0, stream>>>(outpre, out);
}

// Round 7
// 187.235 us; speedup vs baseline: 6.8468x; 1.2450x over previous
//
#include <hip/hip_runtime.h>
#include <hip/hip_bf16.h>
#include <math.h>

#define HW 4096
#define NN 32

typedef __attribute__((ext_vector_type(8))) short bf16x8;
typedef __attribute__((ext_vector_type(4))) float f32x4;

__device__ inline unsigned short bfbits(float a) {
    __hip_bfloat16 h = __float2bfloat16(a);
    unsigned short u;
    __builtin_memcpy(&u, &h, 2);
    return u;
}
__device__ inline unsigned packbf(float a, float b) {
    return (unsigned)bfbits(a) | ((unsigned)bfbits(b) << 16);
}
__device__ inline float bflo(unsigned u) { return __uint_as_float(u << 16); }
__device__ inline float bfhi(unsigned u) { return __uint_as_float(u & 0xffff0000u); }

// ---------------------------------------------------------------------------
// Kernel T: x[n][c][pos] (fp32) -> xT[n][g][pos][c16] (bf16, 32B per pos).
// ---------------------------------------------------------------------------
__global__ __launch_bounds__(256) void transpose_x(const float* __restrict__ x,
                                                   unsigned short* __restrict__ xT)
{
    __shared__ float tile[256 * 17];
    int bx = blockIdx.x;
    int n = bx >> 6, g = (bx >> 4) & 3, chunk = bx & 15;
    int t = threadIdx.x;
    const float* xb = x + (size_t)(n * 64 + g * 16) * HW + chunk * 256;

    #pragma unroll
    for (int r = 0; r < 16; r++) {
        int idx = r * 256 + t;
        int c = idx >> 8, p = idx & 255;
        tile[p * 17 + c] = xb[c * HW + p];
    }
    __syncthreads();

    uint4* ob = (uint4*)(xT + ((size_t)(n * 4 + g) * HW + chunk * 256) * 16);
    #pragma unroll
    for (int r = 0; r < 2; r++) {
        int idx = r * 256 + t;
        int p = idx >> 1, half = idx & 1;
        const float* tp = &tile[p * 17 + half * 8];
        uint4 v;
        v.x = packbf(tp[0], tp[1]);
        v.y = packbf(tp[2], tp[3]);
        v.z = packbf(tp[4], tp[5]);
        v.w = packbf(tp[6], tp[7]);
        ob[idx] = v;
    }
}

// ---------------------------------------------------------------------------
// Bilinear helpers (verified round 3).
// ---------------------------------------------------------------------------
__device__ inline void bilin_setup(int h, int w, int ki, int kj, float dy, float dx,
                                   float* ww, int* ss) {
    float py = (float)(h - 1 + ki) + dy;
    float px = (float)(w - 1 + kj) + dx;
    float y0f = floorf(py), x0f = floorf(px);
    float ly = py - y0f, lx = px - x0f;
    int y0 = (int)y0f, x0 = (int)x0f;
    int y1 = y0 + 1, x1 = x0 + 1;
    float vy0 = (y0 >= 0 && y0 < 64) ? 1.f : 0.f;
    float vy1 = (y1 >= 0 && y1 < 64) ? 1.f : 0.f;
    float vx0 = (x0 >= 0 && x0 < 64) ? 1.f : 0.f;
    float vx1 = (x1 >= 0 && x1 < 64) ? 1.f : 0.f;
    ww[0] = (1.f - ly) * (1.f - lx) * vy0 * vx0;
    ww[1] = (1.f - ly) * lx         * vy0 * vx1;
    ww[2] = ly         * (1.f - lx) * vy1 * vx0;
    ww[3] = ly         * lx         * vy1 * vx1;
    int yc0 = min(max(y0, 0), 63) * 64, yc1 = min(max(y1, 0), 63) * 64;
    int xc0 = min(max(x0, 0), 63),      xc1 = min(max(x1, 0), 63);
    ss[0] = yc0 + xc0; ss[1] = yc0 + xc1; ss[2] = yc1 + xc0; ss[3] = yc1 + xc1;
}

__device__ inline void bilin8(uint4 A, uint4 B, uint4 C, uint4 D,
                              const float* ww, float* val) {
    const unsigned* ua = (const unsigned*)&A;
    const unsigned* ub = (const unsigned*)&B;
    const unsigned* uc = (const unsigned*)&C;
    const unsigned* ud = (const unsigned*)&D;
    #pragma unroll
    for (int j = 0; j < 4; j++) {
        val[2*j]   = ww[0]*bflo(ua[j]) + ww[1]*bflo(ub[j]) + ww[2]*bflo(uc[j]) + ww[3]*bflo(ud[j]);
        val[2*j+1] = ww[0]*bfhi(ua[j]) + ww[1]*bfhi(ub[j]) + ww[2]*bfhi(uc[j]) + ww[3]*bfhi(ud[j]);
    }
}

// ---------------------------------------------------------------------------
// Kernel A4: offset conv, MFMA with A=values (in-register, no LDS tile).
// grid 2048 = 32n*4g*16chunk ; block 256 = 4 waves ; 64 pos/wave (4 subtiles).
// Lane(nn=lane&15, q=lane>>4): A[m=pos(nn)][k=q*8+j], k -> ch=(q&1)*8+j,
// tap=kp*2+(q>>1). A frag = one uint4 of xT. B=weights from LDS.
// D: col=lane&15 -> out channel, row=q*4+r -> pos-in-subtile. No main barriers.
// ---------------------------------------------------------------------------
__global__ __launch_bounds__(256) void off_conv4(const unsigned short* __restrict__ xT,
                                                 const float* __restrict__ w_off,
                                                 const float* __restrict__ b_off,
                                                 __hip_bfloat16* __restrict__ off)
{
    __shared__ float wl[18 * 145];   // [d][c*9+tap], pad 145
    int bx = blockIdx.x;
    int n = bx >> 6, g = (bx >> 4) & 3, chunk = bx & 15;
    int t = threadIdx.x;
    int lane = t & 63, wv = t >> 6;
    int nn = lane & 15, q = lane >> 4;
    int t2 = q >> 1, chh = q & 1;

    for (int idx = t; idx < 2592; idx += 256) {
        int d = idx / 144, rest = idx - d * 144;
        wl[d * 145 + rest] = w_off[(g * 18 + d) * 144 + rest];
    }
    __syncthreads();

    const uint4* xb = (const uint4*)xT + (size_t)(n * 4 + g) * HW * 2;

    f32x4 acc0[4], acc1[4];
    float bv0 = b_off[g * 18 + nn];
    float bv1 = (nn < 2) ? b_off[g * 18 + 16 + nn] : 0.f;
    #pragma unroll
    for (int s = 0; s < 4; s++)
        #pragma unroll
        for (int r = 0; r < 4; r++) { acc0[s][r] = bv0; acc1[s][r] = bv1; }

    #pragma unroll
    for (int kp = 0; kp < 5; kp++) {
        // B fragments: B[k=q*8+j][n-col=o]
        bf16x8 b0, b1;
        #pragma unroll
        for (int j = 0; j < 8; j++) {
            int k = q * 8 + j;
            int c = k & 15, tt = kp * 2 + (k >> 4);
            float w0 = (tt < 9) ? wl[nn * 145 + c * 9 + tt] : 0.f;
            float w1 = (tt < 9 && nn < 2) ? wl[(16 + nn) * 145 + c * 9 + tt] : 0.f;
            b0[j] = (short)bfbits(w0);
            b1[j] = (short)bfbits(w1);
        }
        int tap = kp * 2 + t2;
        int ki = tap / 3, kj = tap - ki * 3;
        #pragma unroll
        for (int s = 0; s < 4; s++) {
            int pos = chunk * 256 + (wv * 4 + s) * 16 + nn;
            int h = pos >> 6, w = pos & 63;
            int r0 = h - 1 + ki, c0 = w - 1 + kj;
            bool valid = (tap < 9) && (r0 >= 0) && (r0 < 64) && (c0 >= 0) && (c0 < 64);
            int idx = valid ? (r0 * 64 + c0) : 0;
            uint4 v = xb[idx * 2 + chh];
            if (!valid) { v.x = v.y = v.z = v.w = 0u; }
            bf16x8 af = *(bf16x8*)&v;
            acc0[s] = __builtin_amdgcn_mfma_f32_16x16x32_bf16(af, b0, acc0[s], 0, 0, 0);
            acc1[s] = __builtin_amdgcn_mfma_f32_16x16x32_bf16(af, b1, acc1[s], 0, 0, 0);
        }
    }

    __hip_bfloat16* ob = off + (size_t)(n * 72 + g * 18) * HW;
    #pragma unroll
    for (int s = 0; s < 4; s++) {
        int pbase = chunk * 256 + (wv * 4 + s) * 16 + q * 4;
        #pragma unroll
        for (int r = 0; r < 4; r++) {
            ob[nn * HW + pbase + r] = __float2bfloat16(acc0[s][r]);
            if (nn < 2)
                ob[(16 + nn) * HW + pbase + r] = __float2bfloat16(acc1[s][r]);
        }
    }
}

// ---------------------------------------------------------------------------
// Kernel B4: deformable conv, MFMA with A=bilinear values (in-register).
// Same lane mapping as A4; per (kp,s) each lane gathers 4 corner uint4s for
// its (pos, tap, ch-half), bilinear-blends 8 channels, packs its A frag.
// No LDS value tile, no main-loop barriers.
// ---------------------------------------------------------------------------
__global__ __launch_bounds__(256) void deform_conv4(const unsigned short* __restrict__ xT,
                                                    const __hip_bfloat16* __restrict__ off,
                                                    const float* __restrict__ w_dc,
                                                    const float* __restrict__ b_dc,
                                                    float* __restrict__ outpre)
{
    __shared__ float wl[16 * 145];   // [o][c*9+tap], pad 145
    int bx = blockIdx.x;
    int n = bx >> 6, g = (bx >> 4) & 3, chunk = bx & 15;
    int t = threadIdx.x;
    int lane = t & 63, wv = t >> 6;
    int nn = lane & 15, q = lane >> 4;
    int t2 = q >> 1, chh = q & 1;

    for (int idx = t; idx < 2304; idx += 256) {
        int d = idx / 144, rest = idx - d * 144;
        wl[d * 145 + rest] = w_dc[(g * 16 + d) * 144 + rest];
    }
    __syncthreads();

    const uint4* xb = (const uint4*)xT + (size_t)(n * 4 + g) * HW * 2;
    const __hip_bfloat16* ob = off + (size_t)(n * 72 + g * 18) * HW;

    f32x4 acc[4];
    float bv = b_dc[g * 16 + nn];
    #pragma unroll
    for (int s = 0; s < 4; s++)
        #pragma unroll
        for (int r = 0; r < 4; r++) acc[s][r] = bv;

    #pragma unroll
    for (int kp = 0; kp < 5; kp++) {
        bf16x8 bw;
        #pragma unroll
        for (int j = 0; j < 8; j++) {
            int k = q * 8 + j;
            int c = k & 15, tt = kp * 2 + (k >> 4);
            float w0 = (tt < 9) ? wl[nn * 145 + c * 9 + tt] : 0.f;
            bw[j] = (short)bfbits(w0);
        }
        int tap = kp * 2 + t2;
        int ki = tap / 3, kj = tap - ki * 3;
        #pragma unroll
        for (int s = 0; s < 4; s++) {
            int pos = chunk * 256 + (wv * 4 + s) * 16 + nn;
            int h = pos >> 6, w = pos & 63;
            bf16x8 af = {0, 0, 0, 0, 0, 0, 0, 0};
            if (tap < 9) {
                float dy = __bfloat162float(ob[(2 * tap + 0) * HW + pos]);
                float dx = __bfloat162float(ob[(2 * tap + 1) * HW + pos]);
                float ww[4]; int ss[4];
                bilin_setup(h, w, ki, kj, dy, dx, ww, ss);
                float val[8];
                bilin8(xb[ss[0] * 2 + chh], xb[ss[1] * 2 + chh],
                       xb[ss[2] * 2 + chh], xb[ss[3] * 2 + chh], ww, val);
                #pragma unroll
                for (int j = 0; j < 8; j++) af[j] = (short)bfbits(val[j]);
            }
            acc[s] = __builtin_amdgcn_mfma_f32_16x16x32_bf16(af, bw, acc[s], 0, 0, 0);
        }
    }

    float* op = outpre + (size_t)(n * 64 + g * 16) * HW;
    #pragma unroll
    for (int s = 0; s < 4; s++) {
        int pbase = chunk * 256 + (wv * 4 + s) * 16 + q * 4;
        #pragma unroll
        for (int r = 0; r < 4; r++)
            op[nn * HW + pbase + r] = acc[s][r];
    }
}

// ---------------------------------------------------------------------------
// Kernel C: per-(n,cout) spatial mean/var + exact GELU + transposed store.
// ---------------------------------------------------------------------------
__global__ __launch_bounds__(256) void norm_gelu(const float* __restrict__ outpre,
                                                 float* __restrict__ out)
{
    __shared__ float red[8];
    int bx = blockIdx.x;
    int n  = bx >> 6;
    int co = bx & 63;
    int t  = threadIdx.x;

    const float4* base = (const float4*)(outpre + (size_t)(n * 64 + co) * HW);
    float4 v[4];
    float s = 0.f;
    #pragma unroll
    for (int r = 0; r < 4; r++) {
        v[r] = base[t + r * 256];
        s += v[r].x + v[r].y + v[r].z + v[r].w;
    }
    #pragma unroll
    for (int o2 = 32; o2 > 0; o2 >>= 1) s += __shfl_down(s, o2, 64);
    int wid = t >> 6, lane = t & 63;
    if (lane == 0) red[wid] = s;
    __syncthreads();
    float mean = (red[0] + red[1] + red[2] + red[3]) * (1.f / 4096.f);

    float sq = 0.f;
    #pragma unroll
    for (int r = 0; r < 4; r++) {
        float a = v[r].x - mean, b = v[r].y - mean;
        float c = v[r].z - mean, d = v[r].w - mean;
        sq += a * a + b * b + c * c + d * d;
    }
    #pragma unroll
    for (int o2 = 32; o2 > 0; o2 >>= 1) sq += __shfl_down(sq, o2, 64);
    if (lane == 0) red[4 + wid] = sq;
    __syncthreads();
    float var  = (red[4] + red[5] + red[6] + red[7]) * (1.f / 4096.f);
    float rstd = rsqrtf(var + 1e-5f);

    int b = n >> 3, d = n & 7;
    float4* outp = (float4*)(out + ((size_t)(b * 64 + co) * 8 + d) * HW);
    #pragma unroll
    for (int r = 0; r < 4; r++) {
        float xs[4] = {v[r].x, v[r].y, v[r].z, v[r].w};
        float4 res;
        float* rp = (float*)&res;
        #pragma unroll
        for (int qq = 0; qq < 4; qq++) {
            float xn = (xs[qq] - mean) * rstd;
            rp[qq] = 0.5f * xn * (1.f + erff(xn * 0.70710678118654752f));
        }
        outp[t + r * 256] = res;
    }
}

// ---------------------------------------------------------------------------
extern "C" void kernel_launch(void* const* d_in, const int* in_sizes, int n_in,
                              void* d_out, int out_size, void* d_ws, size_t ws_size,
                              hipStream_t stream) {
    const float* x     = (const float*)d_in[0];
    const float* w_off = (const float*)d_in[1];
    const float* b_off = (const float*)d_in[2];
    const float* w_dc  = (const float*)d_in[3];
    const float* b_dc  = (const float*)d_in[4];
    float* out = (float*)d_out;

    __hip_bfloat16* xTb  = (__hip_bfloat16*)d_ws;              // 16.78 MB
    __hip_bfloat16* offb = xTb + (size_t)NN * 4 * HW * 16;     // 18.87 MB
    float* outpre = (float*)(offb + (size_t)NN * 72 * HW);     // 33.55 MB

    transpose_x <<<2048, 256, 0, stream>>>(x, (unsigned short*)xTb);
    off_conv4   <<<2048, 256, 0, stream>>>((const unsigned short*)xTb, w_off, b_off, offb);
    deform_conv4<<<2048, 256, 0, stream>>>((const unsigned short*)xTb, offb, w_dc, b_dc, outpre);
    norm_gelu   <<<2048, 256, 0, stream>>>(outpre, out);
}

// Round 8
// 162.248 us; speedup vs baseline: 7.9013x; 1.1540x over previous
//
#include <hip/hip_runtime.h>
#include <hip/hip_bf16.h>
#include <math.h>

#define HW 4096
#define NN 32

typedef __attribute__((ext_vector_type(8))) short bf16x8;
typedef __attribute__((ext_vector_type(4))) float f32x4;

__device__ inline unsigned short bfbits(float a) {
    __hip_bfloat16 h = __float2bfloat16(a);
    unsigned short u;
    __builtin_memcpy(&u, &h, 2);
    return u;
}
__device__ inline unsigned packbf(float a, float b) {
    return (unsigned)bfbits(a) | ((unsigned)bfbits(b) << 16);
}
__device__ inline float bflo(unsigned u) { return __uint_as_float(u << 16); }
__device__ inline float bfhi(unsigned u) { return __uint_as_float(u & 0xffff0000u); }

// ---------------------------------------------------------------------------
// Kernel T: x[n][c][pos] (fp32) -> xT[n][g][pos][c16] (bf16, 32B per pos).
// ---------------------------------------------------------------------------
__global__ __launch_bounds__(256) void transpose_x(const float* __restrict__ x,
                                                   unsigned short* __restrict__ xT)
{
    __shared__ float tile[256 * 17];
    int bx = blockIdx.x;
    int n = bx >> 6, g = (bx >> 4) & 3, chunk = bx & 15;
    int t = threadIdx.x;
    const float* xb = x + (size_t)(n * 64 + g * 16) * HW + chunk * 256;

    #pragma unroll
    for (int r = 0; r < 16; r++) {
        int idx = r * 256 + t;
        int c = idx >> 8, p = idx & 255;
        tile[p * 17 + c] = xb[c * HW + p];
    }
    __syncthreads();

    uint4* ob = (uint4*)(xT + ((size_t)(n * 4 + g) * HW + chunk * 256) * 16);
    #pragma unroll
    for (int r = 0; r < 2; r++) {
        int idx = r * 256 + t;
        int p = idx >> 1, half = idx & 1;
        const float* tp = &tile[p * 17 + half * 8];
        uint4 v;
        v.x = packbf(tp[0], tp[1]);
        v.y = packbf(tp[2], tp[3]);
        v.z = packbf(tp[4], tp[5]);
        v.w = packbf(tp[6], tp[7]);
        ob[idx] = v;
    }
}

// ---------------------------------------------------------------------------
// Bilinear helpers (verified round 3).
// ---------------------------------------------------------------------------
__device__ inline void bilin_setup(int h, int w, int ki, int kj, float dy, float dx,
                                   float* ww, int* ss) {
    float py = (float)(h - 1 + ki) + dy;
    float px = (float)(w - 1 + kj) + dx;
    float y0f = floorf(py), x0f = floorf(px);
    float ly = py - y0f, lx = px - x0f;
    int y0 = (int)y0f, x0 = (int)x0f;
    int y1 = y0 + 1, x1 = x0 + 1;
    float vy0 = (y0 >= 0 && y0 < 64) ? 1.f : 0.f;
    float vy1 = (y1 >= 0 && y1 < 64) ? 1.f : 0.f;
    float vx0 = (x0 >= 0 && x0 < 64) ? 1.f : 0.f;
    float vx1 = (x1 >= 0 && x1 < 64) ? 1.f : 0.f;
    ww[0] = (1.f - ly) * (1.f - lx) * vy0 * vx0;
    ww[1] = (1.f - ly) * lx         * vy0 * vx1;
    ww[2] = ly         * (1.f - lx) * vy1 * vx0;
    ww[3] = ly         * lx         * vy1 * vx1;
    int yc0 = min(max(y0, 0), 63) * 64, yc1 = min(max(y1, 0), 63) * 64;
    int xc0 = min(max(x0, 0), 63),      xc1 = min(max(x1, 0), 63);
    ss[0] = yc0 + xc0; ss[1] = yc0 + xc1; ss[2] = yc1 + xc0; ss[3] = yc1 + xc1;
}

__device__ inline void bilin8(uint4 A, uint4 B, uint4 C, uint4 D,
                              const float* ww, float* val) {
    const unsigned* ua = (const unsigned*)&A;
    const unsigned* ub = (const unsigned*)&B;
    const unsigned* uc = (const unsigned*)&C;
    const unsigned* ud = (const unsigned*)&D;
    #pragma unroll
    for (int j = 0; j < 4; j++) {
        val[2*j]   = ww[0]*bflo(ua[j]) + ww[1]*bflo(ub[j]) + ww[2]*bflo(uc[j]) + ww[3]*bflo(ud[j]);
        val[2*j+1] = ww[0]*bfhi(ua[j]) + ww[1]*bfhi(ub[j]) + ww[2]*bfhi(uc[j]) + ww[3]*bfhi(ud[j]);
    }
}

// ---------------------------------------------------------------------------
// Kernel F: fused offset-conv + deformable conv, both as in-register MFMA.
// grid 2048 = 32n*4g*16chunk ; block 256 = 4 waves ; 64 pos/wave.
// Phase 1: off conv via MFMA (A=xT values, B=w_off frags from LDS) ->
//          offsets stored bf16 in LDS (block-local, 256 pos x 18 d).
// Phase 2: deform conv via MFMA (A=bilinear values, B=w_dc frags from LDS).
// Weights pre-permuted into B-fragment order (bf16) at block start:
//   frag(kp,q,nn,j): k=q*8+j, c=k&15, tap=kp*2+(k>>4), value=W[nn][c*9+tap].
// One barrier after staging, one between phases. No other barriers.
// ---------------------------------------------------------------------------
__global__ __launch_bounds__(256) void fused_conv(const unsigned short* __restrict__ xT,
                                                  const float* __restrict__ w_off,
                                                  const float* __restrict__ b_off,
                                                  const float* __restrict__ w_dc,
                                                  const float* __restrict__ b_dc,
                                                  float* __restrict__ outpre)
{
    // [0..2560): w_dc frags ; [2560..5120): w_off tile0 ; [5120..7680): w_off tile1
    __shared__ __attribute__((aligned(16))) unsigned short wfrag[7680];
    __shared__ __attribute__((aligned(4)))  unsigned short off_lds[256 * 20];

    int bx = blockIdx.x;
    int n = bx >> 6, g = (bx >> 4) & 3, chunk = bx & 15;
    int t = threadIdx.x;
    int lane = t & 63, wv = t >> 6;
    int nn = lane & 15, q = lane >> 4;
    int t2 = q >> 1, chh = q & 1;

    // ---- stage weights, permuted into B-fragment order, bf16 ----
    for (int idx = t; idx < 7680; idx += 256) {
        int which = idx / 2560;
        int r = idx - which * 2560;          // ((kp*4+q)*16+nn)*8+j
        int j = r & 7;
        int rest = r >> 3;
        int nn_ = rest & 15;
        rest >>= 4;
        int q_ = rest & 3, kp_ = rest >> 2;
        int k = q_ * 8 + j;
        int c = k & 15, tt = kp_ * 2 + (k >> 4);
        float v = 0.f;
        if (tt < 9) {
            if (which == 0)      v = w_dc[(g * 16 + nn_) * 144 + c * 9 + tt];
            else if (which == 1) v = w_off[(g * 18 + nn_) * 144 + c * 9 + tt];
            else if (nn_ < 2)    v = w_off[(g * 18 + 16 + nn_) * 144 + c * 9 + tt];
        }
        wfrag[idx] = bfbits(v);
    }
    __syncthreads();

    const uint4* xb = (const uint4*)xT + (size_t)(n * 4 + g) * HW * 2;

    // ================= Phase 1: offset conv =================
    {
        f32x4 acc0[4], acc1[4];
        float bv0 = b_off[g * 18 + nn];
        float bv1 = (nn < 2) ? b_off[g * 18 + 16 + nn] : 0.f;
        #pragma unroll
        for (int s = 0; s < 4; s++)
            #pragma unroll
            for (int r = 0; r < 4; r++) { acc0[s][r] = bv0; acc1[s][r] = bv1; }

        #pragma unroll
        for (int kp = 0; kp < 5; kp++) {
            int fo = ((kp * 4 + q) * 16 + nn) * 8;
            bf16x8 b0 = *(const bf16x8*)&wfrag[2560 + fo];
            bf16x8 b1 = *(const bf16x8*)&wfrag[5120 + fo];
            int tap = kp * 2 + t2;
            int ki = tap / 3, kj = tap - ki * 3;
            #pragma unroll
            for (int s = 0; s < 4; s++) {
                int pos = chunk * 256 + (wv * 4 + s) * 16 + nn;
                int h = pos >> 6, w = pos & 63;
                int r0 = h - 1 + ki, c0 = w - 1 + kj;
                bool valid = (tap < 9) && (r0 >= 0) && (r0 < 64) && (c0 >= 0) && (c0 < 64);
                int idx = valid ? (r0 * 64 + c0) : 0;
                uint4 v = xb[idx * 2 + chh];
                if (!valid) { v.x = v.y = v.z = v.w = 0u; }
                bf16x8 af = *(bf16x8*)&v;
                acc0[s] = __builtin_amdgcn_mfma_f32_16x16x32_bf16(af, b0, acc0[s], 0, 0, 0);
                acc1[s] = __builtin_amdgcn_mfma_f32_16x16x32_bf16(af, b1, acc1[s], 0, 0, 0);
            }
        }

        // store offsets to LDS: D col=nn -> d, row=q*4+r -> pos-in-subtile
        #pragma unroll
        for (int s = 0; s < 4; s++) {
            int pl = (wv * 4 + s) * 16 + q * 4;
            #pragma unroll
            for (int r = 0; r < 4; r++) {
                off_lds[(pl + r) * 20 + nn] = bfbits(acc0[s][r]);
                if (nn < 2)
                    off_lds[(pl + r) * 20 + 16 + nn] = bfbits(acc1[s][r]);
            }
        }
    }
    __syncthreads();

    // ================= Phase 2: deformable conv =================
    f32x4 acc[4];
    float bv = b_dc[g * 16 + nn];
    #pragma unroll
    for (int s = 0; s < 4; s++)
        #pragma unroll
        for (int r = 0; r < 4; r++) acc[s][r] = bv;

    #pragma unroll
    for (int kp = 0; kp < 5; kp++) {
        bf16x8 bw = *(const bf16x8*)&wfrag[((kp * 4 + q) * 16 + nn) * 8];
        int tap = kp * 2 + t2;
        int ki = tap / 3, kj = tap - ki * 3;
        #pragma unroll
        for (int s = 0; s < 4; s++) {
            int pl = (wv * 4 + s) * 16 + nn;
            int pos = chunk * 256 + pl;
            int h = pos >> 6, w = pos & 63;
            bf16x8 af = {0, 0, 0, 0, 0, 0, 0, 0};
            if (tap < 9) {
                unsigned u = *(const unsigned*)&off_lds[pl * 20 + 2 * tap];
                float dy = bflo(u), dx = bfhi(u);
                float ww[4]; int ss[4];
                bilin_setup(h, w, ki, kj, dy, dx, ww, ss);
                float val[8];
                bilin8(xb[ss[0] * 2 + chh], xb[ss[1] * 2 + chh],
                       xb[ss[2] * 2 + chh], xb[ss[3] * 2 + chh], ww, val);
                #pragma unroll
                for (int j = 0; j < 8; j++) af[j] = (short)bfbits(val[j]);
            }
            acc[s] = __builtin_amdgcn_mfma_f32_16x16x32_bf16(af, bw, acc[s], 0, 0, 0);
        }
    }

    float* op = outpre + (size_t)(n * 64 + g * 16) * HW;
    #pragma unroll
    for (int s = 0; s < 4; s++) {
        int pbase = chunk * 256 + (wv * 4 + s) * 16 + q * 4;
        #pragma unroll
        for (int r = 0; r < 4; r++)
            op[nn * HW + pbase + r] = acc[s][r];
    }
}

// ---------------------------------------------------------------------------
// Kernel C: per-(n,cout) spatial mean/var + exact GELU + transposed store.
// ---------------------------------------------------------------------------
__global__ __launch_bounds__(256) void norm_gelu(const float* __restrict__ outpre,
                                                 float* __restrict__ out)
{
    __shared__ float red[8];
    int bx = blockIdx.x;
    int n  = bx >> 6;
    int co = bx & 63;
    int t  = threadIdx.x;

    const float4* base = (const float4*)(outpre + (size_t)(n * 64 + co) * HW);
    float4 v[4];
    float s = 0.f;
    #pragma unroll
    for (int r = 0; r < 4; r++) {
        v[r] = base[t + r * 256];
        s += v[r].x + v[r].y + v[r].z + v[r].w;
    }
    #pragma unroll
    for (int o2 = 32; o2 > 0; o2 >>= 1) s += __shfl_down(s, o2, 64);
    int wid = t >> 6, lane = t & 63;
    if (lane == 0) red[wid] = s;
    __syncthreads();
    float mean = (red[0] + red[1] + red[2] + red[3]) * (1.f / 4096.f);

    float sq = 0.f;
    #pragma unroll
    for (int r = 0; r < 4; r++) {
        float a = v[r].x - mean, b = v[r].y - mean;
        float c = v[r].z - mean, d = v[r].w - mean;
        sq += a * a + b * b + c * c + d * d;
    }
    #pragma unroll
    for (int o2 = 32; o2 > 0; o2 >>= 1) sq += __shfl_down(sq, o2, 64);
    if (lane == 0) red[4 + wid] = sq;
    __syncthreads();
    float var  = (red[4] + red[5] + red[6] + red[7]) * (1.f / 4096.f);
    float rstd = rsqrtf(var + 1e-5f);

    int b = n >> 3, d = n & 7;
    float4* outp = (float4*)(out + ((size_t)(b * 64 + co) * 8 + d) * HW);
    #pragma unroll
    for (int r = 0; r < 4; r++) {
        float xs[4] = {v[r].x, v[r].y, v[r].z, v[r].w};
        float4 res;
        float* rp = (float*)&res;
        #pragma unroll
        for (int qq = 0; qq < 4; qq++) {
            float xn = (xs[qq] - mean) * rstd;
            rp[qq] = 0.5f * xn * (1.f + erff(xn * 0.70710678118654752f));
        }
        outp[t + r * 256] = res;
    }
}

// ---------------------------------------------------------------------------
extern "C" void kernel_launch(void* const* d_in, const int* in_sizes, int n_in,
                              void* d_out, int out_size, void* d_ws, size_t ws_size,
                              hipStream_t stream) {
    const float* x     = (const float*)d_in[0];
    const float* w_off = (const float*)d_in[1];
    const float* b_off = (const float*)d_in[2];
    const float* w_dc  = (const float*)d_in[3];
    const float* b_dc  = (const float*)d_in[4];
    float* out = (float*)d_out;

    __hip_bfloat16* xTb = (__hip_bfloat16*)d_ws;               // 16.78 MB
    float* outpre = (float*)(xTb + (size_t)NN * 4 * HW * 16);  // 33.55 MB

    transpose_x<<<2048, 256, 0, stream>>>(x, (unsigned short*)xTb);
    fused_conv <<<2048, 256, 0, stream>>>((const unsigned short*)xTb,
                                          w_off, b_off, w_dc, b_dc, outpre);
    norm_gelu  <<<2048, 256, 0, stream>>>(outpre, out);
}

// Round 9
// 148.419 us; speedup vs baseline: 8.6375x; 1.0932x over previous
//
#include <hip/hip_runtime.h>
#include <hip/hip_bf16.h>
#include <math.h>

#define HW 4096
#define NN 32
#define W68 68
#define SLICE (68 * 68)   // padded positions per (n,g)

typedef __attribute__((ext_vector_type(8))) short bf16x8;
typedef __attribute__((ext_vector_type(4))) float f32x4;

__device__ inline unsigned short bfbits(float a) {
    __hip_bfloat16 h = __float2bfloat16(a);
    unsigned short u;
    __builtin_memcpy(&u, &h, 2);
    return u;
}
__device__ inline unsigned packbf(float a, float b) {
    return (unsigned)bfbits(a) | ((unsigned)bfbits(b) << 16);
}
__device__ inline float bflo(unsigned u) { return __uint_as_float(u << 16); }
__device__ inline float bfhi(unsigned u) { return __uint_as_float(u & 0xffff0000u); }

__device__ inline void bilin8(uint4 A, uint4 B, uint4 C, uint4 D,
                              const float* ww, float* val) {
    const unsigned* ua = (const unsigned*)&A;
    const unsigned* ub = (const unsigned*)&B;
    const unsigned* uc = (const unsigned*)&C;
    const unsigned* ud = (const unsigned*)&D;
    #pragma unroll
    for (int j = 0; j < 4; j++) {
        val[2*j]   = ww[0]*bflo(ua[j]) + ww[1]*bflo(ub[j]) + ww[2]*bflo(uc[j]) + ww[3]*bflo(ud[j]);
        val[2*j+1] = ww[0]*bfhi(ua[j]) + ww[1]*bfhi(ub[j]) + ww[2]*bfhi(uc[j]) + ww[3]*bfhi(ud[j]);
    }
}

// ---------------------------------------------------------------------------
// Kernel T: x[n][c][pos] fp32 -> xT[n][g][(h+2)*68+(w+2)][c16] bf16 with a
// 2-cell zero halo (memset provides the zeros). Blocks 0..119 additionally
// build the B-fragment-permuted weight buffer wperm (bf16):
//   wperm[g*7680 + which*2560 + ((kp*4+q)*16+nn)*8 + j],
//   which: 0=w_dc, 1=w_off rows 0..15, 2=w_off rows 16..17,
//   k=q*8+j -> c=k&15, tap=kp*2+(k>>4); zero for tap>=9.
// ---------------------------------------------------------------------------
__global__ __launch_bounds__(256) void transpose_x(const float* __restrict__ x,
                                                   unsigned short* __restrict__ xT,
                                                   const float* __restrict__ w_off,
                                                   const float* __restrict__ w_dc,
                                                   unsigned short* __restrict__ wperm)
{
    int bx = blockIdx.x;
    int t = threadIdx.x;

    if (bx < 120) {
        int idx = bx * 256 + t;                  // < 30720
        int g = idx / 7680;
        int r3 = idx - g * 7680;
        int which = r3 / 2560;
        int r = r3 - which * 2560;
        int j = r & 7;
        int rest = r >> 3;
        int nn_ = rest & 15; rest >>= 4;
        int q_ = rest & 3, kp_ = rest >> 2;
        int k = q_ * 8 + j;
        int c = k & 15, tt = kp_ * 2 + (k >> 4);
        float v = 0.f;
        if (tt < 9) {
            if (which == 0)      v = w_dc[(g * 16 + nn_) * 144 + c * 9 + tt];
            else if (which == 1) v = w_off[(g * 18 + nn_) * 144 + c * 9 + tt];
            else if (nn_ < 2)    v = w_off[(g * 18 + 16 + nn_) * 144 + c * 9 + tt];
        }
        wperm[idx] = bfbits(v);
    }

    __shared__ float tile[256 * 17];
    int n = bx >> 6, g = (bx >> 4) & 3, chunk = bx & 15;
    const float* xb = x + (size_t)(n * 64 + g * 16) * HW + chunk * 256;

    #pragma unroll
    for (int r = 0; r < 16; r++) {
        int idx = r * 256 + t;
        int c = idx >> 8, p = idx & 255;
        tile[p * 17 + c] = xb[c * HW + p];
    }
    __syncthreads();

    unsigned short* ob = xT + (size_t)(n * 4 + g) * SLICE * 16;
    #pragma unroll
    for (int r = 0; r < 2; r++) {
        int idx = r * 256 + t;
        int p = idx >> 1, half = idx & 1;
        int pos = chunk * 256 + p;
        int h = pos >> 6, w = pos & 63;
        const float* tp = &tile[p * 17 + half * 8];
        uint4 v;
        v.x = packbf(tp[0], tp[1]);
        v.y = packbf(tp[2], tp[3]);
        v.z = packbf(tp[4], tp[5]);
        v.w = packbf(tp[6], tp[7]);
        *(uint4*)(ob + ((size_t)((h + 2) * W68 + (w + 2)) * 16 + half * 8)) = v;
    }
}

// ---------------------------------------------------------------------------
// Kernel F: fused offset-conv + deformable conv, in-register MFMA, halo'd xT.
// grid 2048 = 32n*4g*16chunk ; block 256 = 4 waves ; 64 pos/wave.
// No validity logic anywhere: halo zeros implement both conv zero-padding and
// bilinear corner invalidation (floor clamped to [-2,64]).
// ---------------------------------------------------------------------------
__global__ __launch_bounds__(256) void fused_conv(const unsigned short* __restrict__ xT,
                                                  const unsigned short* __restrict__ wperm,
                                                  const float* __restrict__ b_off,
                                                  const float* __restrict__ b_dc,
                                                  float* __restrict__ outpre)
{
    __shared__ __attribute__((aligned(16))) unsigned short wfrag[7680];
    __shared__ __attribute__((aligned(4)))  unsigned short off_lds[256 * 20];

    int bx = blockIdx.x;
    int n = bx >> 6, g = (bx >> 4) & 3, chunk = bx & 15;
    int t = threadIdx.x;
    int lane = t & 63, wv = t >> 6;
    int nn = lane & 15, q = lane >> 4;
    int t2 = q >> 1, chh = q & 1;

    // stage pre-permuted weights: pure coalesced copy, no decode
    {
        const uint4* src = (const uint4*)(wperm + g * 7680);
        uint4* dst = (uint4*)wfrag;
        #pragma unroll
        for (int r = 0; r < 4; r++) {
            int idx = r * 256 + t;
            if (idx < 960) dst[idx] = src[idx];
        }
    }
    __syncthreads();

    const unsigned short* xw = xT + (size_t)(n * 4 + g) * SLICE * 16 + chh * 8;

    // ================= Phase 1: offset conv =================
    {
        f32x4 acc0[4], acc1[4];
        float bv0 = b_off[g * 18 + nn];
        float bv1 = (nn < 2) ? b_off[g * 18 + 16 + nn] : 0.f;
        #pragma unroll
        for (int s = 0; s < 4; s++)
            #pragma unroll
            for (int r = 0; r < 4; r++) { acc0[s][r] = bv0; acc1[s][r] = bv1; }

        #pragma unroll
        for (int kp = 0; kp < 5; kp++) {
            int fo = ((kp * 4 + q) * 16 + nn) * 8;
            bf16x8 b0 = *(const bf16x8*)&wfrag[2560 + fo];
            bf16x8 b1 = *(const bf16x8*)&wfrag[5120 + fo];
            int tap = kp * 2 + t2;                 // tap==9: loads real data,
            int ki = tap / 3, kj = tap - ki * 3;   // but b0/b1 slots are zero
            #pragma unroll
            for (int s = 0; s < 4; s++) {
                int pos = chunk * 256 + (wv * 4 + s) * 16 + nn;
                int h = pos >> 6, w = pos & 63;
                int base = (h + 1 + ki) * W68 + (w + 1 + kj);   // (h-1+ki+2), in-bounds
                uint4 v = *(const uint4*)(xw + (size_t)base * 16);
                bf16x8 af = *(bf16x8*)&v;
                acc0[s] = __builtin_amdgcn_mfma_f32_16x16x32_bf16(af, b0, acc0[s], 0, 0, 0);
                acc1[s] = __builtin_amdgcn_mfma_f32_16x16x32_bf16(af, b1, acc1[s], 0, 0, 0);
            }
        }

        #pragma unroll
        for (int s = 0; s < 4; s++) {
            int pl = (wv * 4 + s) * 16 + q * 4;
            #pragma unroll
            for (int r = 0; r < 4; r++) {
                off_lds[(pl + r) * 20 + nn] = bfbits(acc0[s][r]);
                if (nn < 2)
                    off_lds[(pl + r) * 20 + 16 + nn] = bfbits(acc1[s][r]);
            }
        }
    }
    __syncthreads();

    // ================= Phase 2: deformable conv =================
    f32x4 acc[4];
    float bv = b_dc[g * 16 + nn];
    #pragma unroll
    for (int s = 0; s < 4; s++)
        #pragma unroll
        for (int r = 0; r < 4; r++) acc[s][r] = bv;

    #pragma unroll
    for (int kp = 0; kp < 5; kp++) {
        bf16x8 bw = *(const bf16x8*)&wfrag[((kp * 4 + q) * 16 + nn) * 8];
        int tap = kp * 2 + t2;
        int ki = tap / 3, kj = tap - ki * 3;
        #pragma unroll
        for (int s = 0; s < 4; s++) {
            int pl = (wv * 4 + s) * 16 + nn;
            int pos = chunk * 256 + pl;
            int h = pos >> 6, w = pos & 63;
            bf16x8 af = {0, 0, 0, 0, 0, 0, 0, 0};
            if (tap < 9) {
                unsigned u = *(const unsigned*)&off_lds[pl * 20 + 2 * tap];
                float py = (float)(h - 1 + ki) + bflo(u);
                float px = (float)(w - 1 + kj) + bfhi(u);
                float y0f = fminf(fmaxf(floorf(py), -2.f), 64.f);
                float x0f = fminf(fmaxf(floorf(px), -2.f), 64.f);
                float ly = py - y0f, lx = px - x0f;
                float my = 1.f - ly, mx = 1.f - lx;
                float ww[4] = { my * mx, my * lx, ly * mx, ly * lx };
                int y0 = (int)y0f, x0 = (int)x0f;
                int base = (y0 + 2) * W68 + (x0 + 2);
                const unsigned short* p0 = xw + (size_t)base * 16;
                uint4 A = *(const uint4*)(p0);
                uint4 B = *(const uint4*)(p0 + 16);
                uint4 C = *(const uint4*)(p0 + W68 * 16);
                uint4 D = *(const uint4*)(p0 + W68 * 16 + 16);
                float val[8];
                bilin8(A, B, C, D, ww, val);
                #pragma unroll
                for (int j = 0; j < 8; j++) af[j] = (short)bfbits(val[j]);
            }
            acc[s] = __builtin_amdgcn_mfma_f32_16x16x32_bf16(af, bw, acc[s], 0, 0, 0);
        }
    }

    float* op = outpre + (size_t)(n * 64 + g * 16) * HW;
    #pragma unroll
    for (int s = 0; s < 4; s++) {
        int pbase = chunk * 256 + (wv * 4 + s) * 16 + q * 4;
        #pragma unroll
        for (int r = 0; r < 4; r++)
            op[nn * HW + pbase + r] = acc[s][r];
    }
}

// ---------------------------------------------------------------------------
// Kernel C: per-(n,cout) mean/var (single pass) + sigmoid-form tanh GELU.
// ---------------------------------------------------------------------------
__global__ __launch_bounds__(256) void norm_gelu(const float* __restrict__ outpre,
                                                 float* __restrict__ out)
{
    __shared__ float red[8];
    int bx = blockIdx.x;
    int n  = bx >> 6;
    int co = bx & 63;
    int t  = threadIdx.x;

    const float4* base = (const float4*)(outpre + (size_t)(n * 64 + co) * HW);
    float4 v[4];
    float s = 0.f, sq = 0.f;
    #pragma unroll
    for (int r = 0; r < 4; r++) {
        v[r] = base[t + r * 256];
        s  += v[r].x + v[r].y + v[r].z + v[r].w;
        sq  = fmaf(v[r].x, v[r].x, sq);
        sq  = fmaf(v[r].y, v[r].y, sq);
        sq  = fmaf(v[r].z, v[r].z, sq);
        sq  = fmaf(v[r].w, v[r].w, sq);
    }
    #pragma unroll
    for (int o2 = 32; o2 > 0; o2 >>= 1) {
        s  += __shfl_down(s,  o2, 64);
        sq += __shfl_down(sq, o2, 64);
    }
    int wid = t >> 6, lane = t & 63;
    if (lane == 0) { red[wid] = s; red[4 + wid] = sq; }
    __syncthreads();
    float S  = red[0] + red[1] + red[2] + red[3];
    float SQ = red[4] + red[5] + red[6] + red[7];
    float mean = S * (1.f / 4096.f);
    float var  = SQ * (1.f / 4096.f) - mean * mean;
    float rstd = rsqrtf(var + 1e-5f);

    int b = n >> 3, d = n & 7;
    float4* outp = (float4*)(out + ((size_t)(b * 64 + co) * 8 + d) * HW);
    #pragma unroll
    for (int r = 0; r < 4; r++) {
        float xs[4] = {v[r].x, v[r].y, v[r].z, v[r].w};
        float4 res;
        float* rp = (float*)&res;
        #pragma unroll
        for (int qq = 0; qq < 4; qq++) {
            float xn = (xs[qq] - mean) * rstd;
            float u = xn * (1.5957691f + 0.0713548162f * xn * xn);
            float e = __expf(-u);
            rp[qq] = xn * __frcp_rn(1.f + e);
        }
        outp[t + r * 256] = res;
    }
}

// ---------------------------------------------------------------------------
extern "C" void kernel_launch(void* const* d_in, const int* in_sizes, int n_in,
                              void* d_out, int out_size, void* d_ws, size_t ws_size,
                              hipStream_t stream) {
    const float* x     = (const float*)d_in[0];
    const float* w_off = (const float*)d_in[1];
    const float* b_off = (const float*)d_in[2];  (void)b_off;
    const float* w_dc  = (const float*)d_in[3];
    const float* b_dc  = (const float*)d_in[4];
    float* out = (float*)d_out;

    unsigned short* wperm = (unsigned short*)d_ws;                   // 61,440 B
    unsigned short* xTb   = wperm + 30720;                           // 18.94 MB
    float* outpre = (float*)(xTb + (size_t)NN * 4 * SLICE * 16);     // 33.55 MB

    // zero wperm + halo'd xT (interior overwritten by transpose_x)
    hipMemsetAsync(d_ws, 0, 61440 + (size_t)NN * 4 * SLICE * 16 * 2, stream);

    transpose_x<<<2048, 256, 0, stream>>>(x, xTb, w_off, w_dc, wperm);
    fused_conv <<<2048, 256, 0, stream>>>(xTb, wperm,
                                          (const float*)d_in[2], b_dc, outpre);
    norm_gelu  <<<2048, 256, 0, stream>>>(outpre, out);
}